// Round 1
// baseline (30940.155 us; speedup 1.0000x reference)
//
#include <hip/hip_runtime.h>
#include <hip/hip_fp16.h>

// Speller (LAS decoder): 3x LSTMCell + dot attention + CDN head.
// B=128 S=600 T=200 ENC=512 P=128 E=256 H=512 V=31.
// Round 1: fp32 baseline, multi-launch graph (802 nodes).
//   - key/value projected once (fp16 storage, 39 MB in d_ws)
//   - per step: cell0, cell1, cell2, attn+cdn kernels
//   - h double-buffered across steps (cross-block WAR hazard on in-place h)
//   - c updated in place (strict per-thread (unit,b) ownership)
// d_ws requirement: ~41.8 MB.

#define Bc 128
#define Sc 600
#define Tc 200
#define ENCc 512
#define Pc 128
#define Ec 256
#define Hc 512
#define Vc 31

__device__ __forceinline__ float sigmoidf_(float x) { return 1.f / (1.f + expf(-x)); }

// ---------------- init: copy h0/c0 into state, zero ctx ----------------
__global__ __launch_bounds__(256) void init_kernel(
    const float* __restrict__ h0, const float* __restrict__ c0,
    float* __restrict__ hbuf, float* __restrict__ cst, float* __restrict__ ctx)
{
  const int i = blockIdx.x * 256 + threadIdx.x;
  if (i < 3 * Bc * Hc) { hbuf[i] = h0[i]; cst[i] = c0[i]; }
  if (i < Bc * Pc) ctx[i] = 0.f;
}

// ---------------- key/value projection (once) ----------------
// key[b,s,p] = x[b,s,:]@KW_w[p,:] + KW_b[p]  (fp16 out), same for value.
__global__ __launch_bounds__(256) void kv_kernel(
    const float* __restrict__ x,
    const float* __restrict__ KW_w, const float* __restrict__ KW_b,
    const float* __restrict__ VW_w, const float* __restrict__ VW_b,
    __half* __restrict__ key16, __half* __restrict__ val16)
{
  const int r0 = blockIdx.x * 32;   // 32 rows (b*600+s) per block
  const int tid = threadIdx.x;
  const bool isv = tid >= 128;
  const int p = tid & 127;
  const float* __restrict__ W = isv ? VW_w : KW_w;
  float acc[32];
#pragma unroll
  for (int r = 0; r < 32; ++r) acc[r] = 0.f;
  __shared__ float xs[32][64];
  for (int c = 0; c < 8; ++c) {
    const int k0 = c * 64;
    __syncthreads();
#pragma unroll
    for (int i = 0; i < 2; ++i) {
      const int e = i * 256 + tid;          // 512 float4 slots
      const int row = e >> 4, c4 = e & 15;
      *(float4*)(&xs[row][c4 * 4]) =
          *(const float4*)(x + (size_t)(r0 + row) * ENCc + k0 + c4 * 4);
    }
    __syncthreads();
    const float* wr = W + (size_t)p * ENCc + k0;
#pragma unroll
    for (int kk = 0; kk < 16; ++kk) {
      const float4 w4 = *(const float4*)(wr + kk * 4);
#pragma unroll
      for (int r = 0; r < 32; ++r) {
        const float4 xv = *(const float4*)(&xs[r][kk * 4]);
        acc[r] += w4.x * xv.x + w4.y * xv.y + w4.z * xv.z + w4.w * xv.w;
      }
    }
  }
  const float bias = isv ? VW_b[p] : KW_b[p];
  __half* __restrict__ dst = isv ? val16 : key16;
#pragma unroll
  for (int r = 0; r < 32; ++r)
    dst[(size_t)(r0 + r) * Pc + p] = __float2half(acc[r] + bias);
}

// ---------------- LSTM cell kernel ----------------
// Block: 8 hidden-units (u0..u0+7) x 32 batch rows (b0..b0+31).
// 512 threads: tid = jq*64 + bq*8 + kg ; jq(unit)=wave, bq=4-b-group, kg=k-split 8.
// Thread accумs acc[gate][bb] over its k-slice; shfl_xor reduce over kg;
// kg==0 lanes apply bias+nonlinearity, update c in place, write h_new.
#define CHUNK_COMPUTE(W0_, W1_, W2_, W3_, K0_)                                   \
  {                                                                              \
    _Pragma("unroll") for (int m = 0; m < 4; ++m)                                \
    {                                                                            \
      const int kl = kg * 4 + m * 32;                                            \
      const float4 a0 = *(const float4*)((W0_) + (K0_) + kl);                    \
      const float4 a1 = *(const float4*)((W1_) + (K0_) + kl);                    \
      const float4 a2 = *(const float4*)((W2_) + (K0_) + kl);                    \
      const float4 a3 = *(const float4*)((W3_) + (K0_) + kl);                    \
      _Pragma("unroll") for (int bb = 0; bb < 4; ++bb)                           \
      {                                                                          \
        const float4 xv = *(const float4*)(&xs[bq * 4 + bb][kl]);                \
        acc[0][bb] += a0.x * xv.x + a0.y * xv.y + a0.z * xv.z + a0.w * xv.w;     \
        acc[1][bb] += a1.x * xv.x + a1.y * xv.y + a1.z * xv.z + a1.w * xv.w;     \
        acc[2][bb] += a2.x * xv.x + a2.y * xv.y + a2.z * xv.z + a2.w * xv.w;     \
        acc[3][bb] += a3.x * xv.x + a3.y * xv.y + a3.z * xv.z + a3.w * xv.w;     \
      }                                                                          \
    }                                                                            \
  }

template <int CELL>
__global__ __launch_bounds__(512) void cell_kernel(
    const float* __restrict__ W_ih, const float* __restrict__ W_hh,
    const float* __restrict__ b_ih, const float* __restrict__ b_hh,
    const float* __restrict__ emb, const int* __restrict__ y,
    const float* __restrict__ ctx,
    const float* __restrict__ hold, float* __restrict__ hnew,
    float* __restrict__ cst, const int t)
{
  constexpr int K1 = (CELL == 0) ? 384 : 512;   // input-side K
  const int u0 = blockIdx.x * 8, b0 = blockIdx.y * 32;
  const int tid = threadIdx.x;
  const int kg = tid & 7, bq = (tid >> 3) & 7, jq = tid >> 6;
  const int u = u0 + jq;
  float acc[4][4] = {{0.f,0.f,0.f,0.f},{0.f,0.f,0.f,0.f},{0.f,0.f,0.f,0.f},{0.f,0.f,0.f,0.f}};
  __shared__ float xs[32][132];   // stride 132 to spread banks

  // ---- segment 1: W_ih * x_in ----
  {
    const float* w0 = W_ih + (size_t)(u)        * K1;
    const float* w1 = W_ih + (size_t)(u + 512)  * K1;
    const float* w2 = W_ih + (size_t)(u + 1024) * K1;
    const float* w3 = W_ih + (size_t)(u + 1536) * K1;
#pragma unroll
    for (int c = 0; c < K1 / 128; ++c) {
      const int k0 = c * 128;
      __syncthreads();
#pragma unroll
      for (int i = 0; i < 2; ++i) {
        const int e = i * 512 + tid;          // 1024 float4 slots
        const int row = e >> 5, c4 = e & 31;
        const int k = k0 + c4 * 4;
        const int b = b0 + row;
        float4 v;
        if (CELL == 0) {
          if (k < 256) {
            const int tok = (t == 0) ? 1 : y[b * Tc + t - 1];
            v = *(const float4*)(emb + (size_t)tok * Ec + k);
          } else {
            v = *(const float4*)(ctx + (size_t)b * Pc + (k - 256));
          }
        } else {
          v = *(const float4*)(hnew + (size_t)(CELL - 1) * (Bc * Hc) + (size_t)b * Hc + k);
        }
        *(float4*)(&xs[row][c4 * 4]) = v;
      }
      __syncthreads();
      CHUNK_COMPUTE(w0, w1, w2, w3, k0)
    }
  }
  // ---- segment 2: W_hh * h_old ----
  {
    const float* w0 = W_hh + (size_t)(u)        * Hc;
    const float* w1 = W_hh + (size_t)(u + 512)  * Hc;
    const float* w2 = W_hh + (size_t)(u + 1024) * Hc;
    const float* w3 = W_hh + (size_t)(u + 1536) * Hc;
    const float* hsrc = hold + (size_t)CELL * (Bc * Hc);
#pragma unroll
    for (int c = 0; c < 4; ++c) {
      const int k0 = c * 128;
      __syncthreads();
#pragma unroll
      for (int i = 0; i < 2; ++i) {
        const int e = i * 512 + tid;
        const int row = e >> 5, c4 = e & 31;
        *(float4*)(&xs[row][c4 * 4]) =
            *(const float4*)(hsrc + (size_t)(b0 + row) * Hc + k0 + c4 * 4);
      }
      __syncthreads();
      CHUNK_COMPUTE(w0, w1, w2, w3, k0)
    }
  }
  // ---- reduce over kg (lanes tid^1, tid^2, tid^4) ----
#pragma unroll
  for (int g = 0; g < 4; ++g) {
#pragma unroll
    for (int bb = 0; bb < 4; ++bb) {
      float v = acc[g][bb];
      v += __shfl_xor(v, 1);
      v += __shfl_xor(v, 2);
      v += __shfl_xor(v, 4);
      acc[g][bb] = v;
    }
  }
  if (kg == 0) {
    const float bi = b_ih[u]        + b_hh[u];
    const float bf = b_ih[u + 512]  + b_hh[u + 512];
    const float bg = b_ih[u + 1024] + b_hh[u + 1024];
    const float bo = b_ih[u + 1536] + b_hh[u + 1536];
    float* hn = hnew + (size_t)CELL * (Bc * Hc);
    float* cs = cst  + (size_t)CELL * (Bc * Hc);
#pragma unroll
    for (int bb = 0; bb < 4; ++bb) {
      const int b = b0 + bq * 4 + bb;
      const int idx = b * Hc + u;
      const float ig = sigmoidf_(acc[0][bb] + bi);
      const float fg = sigmoidf_(acc[1][bb] + bf);
      const float gg = tanhf(acc[2][bb] + bg);
      const float og = sigmoidf_(acc[3][bb] + bo);
      const float cn = fg * cs[idx] + ig * gg;
      cs[idx] = cn;
      hn[idx] = og * tanhf(cn);
    }
  }
}

// ---------------- attention + CDN head (one block per batch row) ----------------
__device__ __forceinline__ float wave_max_(float v) {
#pragma unroll
  for (int o = 32; o; o >>= 1) v = fmaxf(v, __shfl_xor(v, o));
  return v;
}
__device__ __forceinline__ float wave_sum_(float v) {
#pragma unroll
  for (int o = 32; o; o >>= 1) v += __shfl_xor(v, o);
  return v;
}

__global__ __launch_bounds__(256) void attn_cdn_kernel(
    const float* __restrict__ hnew,
    const __half* __restrict__ key16, const __half* __restrict__ val16,
    const int* __restrict__ enc_lens,
    const float* __restrict__ QW_w, const float* __restrict__ QW_b,
    const float* __restrict__ out_w, const float* __restrict__ out_b,
    const float* __restrict__ char_w, const float* __restrict__ char_b,
    float* __restrict__ ctx_out, float* __restrict__ raw_out,
    float* __restrict__ attn_out, const int t)
{
  const int b = blockIdx.x, tid = threadIdx.x;
  __shared__ float h2s[Hc], qs[Pc], wsm[Sc], ctxs[Pc], hid[Ec];
  __shared__ float s_red[4];
  const float* h2 = hnew + 2 * (Bc * Hc) + (size_t)b * Hc;
  for (int i = tid; i < Hc; i += 256) h2s[i] = h2[i];
  __syncthreads();
  // q = h2 @ QW^T + QW_b
  if (tid < Pc) {
    const float* wr = QW_w + (size_t)tid * Hc;
    float a = QW_b[tid];
#pragma unroll 8
    for (int k = 0; k < Hc; k += 4) {
      const float4 w = *(const float4*)(wr + k);
      a += w.x * h2s[k] + w.y * h2s[k + 1] + w.z * h2s[k + 2] + w.w * h2s[k + 3];
    }
    qs[tid] = a;
  }
  __syncthreads();
  const int len = enc_lens[b];
  // scores
  float lmax = -3.0e38f;
  for (int s = tid; s < Sc; s += 256) {
    if (s < len) {
      const __half* kr = key16 + ((size_t)(b * Sc + s)) * Pc;
      float a = 0.f;
#pragma unroll 16
      for (int p = 0; p < Pc; p += 4) {
        const float2 k01 = __half22float2(*(const __half2*)(kr + p));
        const float2 k23 = __half22float2(*(const __half2*)(kr + p + 2));
        a += k01.x * qs[p] + k01.y * qs[p + 1] + k23.x * qs[p + 2] + k23.y * qs[p + 3];
      }
      const float sc = a * 0.08838834764831845f;  // 1/sqrt(128)
      wsm[s] = sc;
      lmax = fmaxf(lmax, sc);
    }
  }
  float wm = wave_max_(lmax);
  if ((tid & 63) == 0) s_red[tid >> 6] = wm;
  __syncthreads();
  const float mx = fmaxf(fmaxf(s_red[0], s_red[1]), fmaxf(s_red[2], s_red[3]));
  __syncthreads();
  float lsum = 0.f;
  for (int s = tid; s < Sc; s += 256)
    if (s < len) { const float e = expf(wsm[s] - mx); wsm[s] = e; lsum += e; }
  float ws_ = wave_sum_(lsum);
  if ((tid & 63) == 0) s_red[tid >> 6] = ws_;
  __syncthreads();
  const float inv = 1.f / (s_red[0] + s_red[1] + s_red[2] + s_red[3]);
  float* ap = attn_out + ((size_t)(b * Tc + t)) * Sc;
  for (int s = tid; s < Sc; s += 256) {
    const float w = (s < len) ? wsm[s] * inv : 0.f;
    wsm[s] = w;
    ap[s] = w;
  }
  __syncthreads();
  // ctx = w @ value
  if (tid < Pc) {
    const __half* vp = val16 + ((size_t)b * Sc) * Pc + tid;
    float a = 0.f;
#pragma unroll 4
    for (int s = 0; s < len; ++s) a += wsm[s] * __half2float(vp[(size_t)s * Pc]);
    ctxs[tid] = a;
    ctx_out[b * Pc + tid] = a;
  }
  __syncthreads();
  // hidden = gelu([h2|ctx] @ out_w^T + out_b)
  {
    const float* wr = out_w + (size_t)tid * (Hc + Pc);
    float a = out_b[tid];
#pragma unroll 8
    for (int k = 0; k < Hc; k += 4) {
      const float4 w = *(const float4*)(wr + k);
      a += w.x * h2s[k] + w.y * h2s[k + 1] + w.z * h2s[k + 2] + w.w * h2s[k + 3];
    }
#pragma unroll 8
    for (int k = 0; k < Pc; k += 4) {
      const float4 w = *(const float4*)(wr + Hc + k);
      a += w.x * ctxs[k] + w.y * ctxs[k + 1] + w.z * ctxs[k + 2] + w.w * ctxs[k + 3];
    }
    hid[tid] = 0.5f * a * (1.f + erff(a * 0.70710678118654752440f));  // exact gelu
  }
  __syncthreads();
  // pred = hidden @ char_w^T + char_b
  if (tid < Vc) {
    const float* wr = char_w + (size_t)tid * Ec;
    float a = char_b[tid];
#pragma unroll 8
    for (int k = 0; k < Ec; k += 4) {
      const float4 w = *(const float4*)(wr + k);
      a += w.x * hid[k] + w.y * hid[k + 1] + w.z * hid[k + 2] + w.w * hid[k + 3];
    }
    raw_out[((size_t)(b * Tc + t)) * Vc + tid] = a;
  }
}

extern "C" void kernel_launch(void* const* d_in, const int* in_sizes, int n_in,
                              void* d_out, int out_size, void* d_ws, size_t ws_size,
                              hipStream_t stream) {
  (void)in_sizes; (void)n_in; (void)out_size; (void)ws_size;
  const float* x      = (const float*)d_in[0];
  const int*   y      = (const int*)  d_in[1];
  const int*   enc    = (const int*)  d_in[2];
  const float* h0     = (const float*)d_in[3];
  const float* c0     = (const float*)d_in[4];
  const float* emb    = (const float*)d_in[5];
  const float* W_ih0  = (const float*)d_in[6];
  const float* W_hh0  = (const float*)d_in[7];
  const float* b_ih0  = (const float*)d_in[8];
  const float* b_hh0  = (const float*)d_in[9];
  const float* W_ih1  = (const float*)d_in[10];
  const float* W_hh1  = (const float*)d_in[11];
  const float* b_ih1  = (const float*)d_in[12];
  const float* b_hh1  = (const float*)d_in[13];
  const float* W_ih2  = (const float*)d_in[14];
  const float* W_hh2  = (const float*)d_in[15];
  const float* b_ih2  = (const float*)d_in[16];
  const float* b_hh2  = (const float*)d_in[17];
  const float* KW_w   = (const float*)d_in[18];
  const float* KW_b   = (const float*)d_in[19];
  const float* VW_w   = (const float*)d_in[20];
  const float* VW_b   = (const float*)d_in[21];
  const float* QW_w   = (const float*)d_in[22];
  const float* QW_b   = (const float*)d_in[23];
  const float* out_w  = (const float*)d_in[24];
  const float* out_b  = (const float*)d_in[25];
  const float* char_w = (const float*)d_in[26];
  const float* char_b = (const float*)d_in[27];

  float* out  = (float*)d_out;
  float* raw  = out;                    // (B,T,V) = 793,600
  float* attn = out + 793600;           // (B,T,S) = 15,360,000

  // workspace layout (needs ~41.8 MB)
  char* ws = (char*)d_ws;
  __half* key16 = (__half*)(ws);                       // 19,660,800 B
  __half* val16 = (__half*)(ws + 19660800);            // 19,660,800 B
  float*  hbuf  = (float*) (ws + 39321600);            // 2 x 3*B*H fp32
  float*  cst   = (float*) (ws + 39321600 + 1572864);  // 3*B*H fp32
  float*  ctx   = (float*) (ws + 39321600 + 1572864 + 786432);  // B*P fp32

  init_kernel<<<768, 256, 0, stream>>>(h0, c0, hbuf, cst, ctx);
  kv_kernel<<<2400, 256, 0, stream>>>(x, KW_w, KW_b, VW_w, VW_b, key16, val16);

  for (int t = 0; t < Tc; ++t) {
    float* hold = hbuf + (size_t)(t & 1) * (3 * Bc * Hc);
    float* hnew = hbuf + (size_t)((t & 1) ^ 1) * (3 * Bc * Hc);
    cell_kernel<0><<<dim3(64, 4), 512, 0, stream>>>(W_ih0, W_hh0, b_ih0, b_hh0,
                                                    emb, y, ctx, hold, hnew, cst, t);
    cell_kernel<1><<<dim3(64, 4), 512, 0, stream>>>(W_ih1, W_hh1, b_ih1, b_hh1,
                                                    emb, y, ctx, hold, hnew, cst, t);
    cell_kernel<2><<<dim3(64, 4), 512, 0, stream>>>(W_ih2, W_hh2, b_ih2, b_hh2,
                                                    emb, y, ctx, hold, hnew, cst, t);
    attn_cdn_kernel<<<128, 256, 0, stream>>>(hnew, key16, val16, enc,
                                             QW_w, QW_b, out_w, out_b, char_w, char_b,
                                             ctx, raw, attn, t);
  }
}